// Round 1
// baseline (158.848 us; speedup 1.0000x reference)
//
#include <hip/hip_runtime.h>

// FractionalSTFT round-trip is algebraically the identity:
//  - k2 = {m/16 : m=0..16383}  => W^H W = 16 I (tight frame)
//  - pinv(W) = W^H / 16        => decode(encode(frame)) = frame exactly
//  - Xe concat == conjugate-symmetric extension == W @ frames (real input)
//  - overlap-add of window*xp divided by win_norm = xp; crop => x
// So out = x. One vectorized copy, float4 per lane.
// 2 MiB in + 2 MiB out: memory time ~0.7us at 6.3 TB/s; measured time is
// harness floor, not kernel time.

__global__ __launch_bounds__(256)
void FractionalSTFT_identity_copy(const float4* __restrict__ in,
                                  float4* __restrict__ out, int n4) {
    int i = blockIdx.x * blockDim.x + threadIdx.x;
    if (i < n4) out[i] = in[i];
}

extern "C" void kernel_launch(void* const* d_in, const int* in_sizes, int n_in,
                              void* d_out, int out_size, void* d_ws, size_t ws_size,
                              hipStream_t stream) {
    const float4* x = (const float4*)d_in[0];  // x: (2,2,131072) float32, contiguous
    float4* out = (float4*)d_out;              // same shape/dtype
    int n4 = out_size / 4;                     // elements/4 -> float4 count
    const int block = 256;
    int grid = (n4 + block - 1) / block;
    FractionalSTFT_identity_copy<<<grid, block, 0, stream>>>(x, out, n4);
}